// Round 12
// baseline (33.428 us; speedup 1.0000x reference)
//
#include <hip/hip_runtime.h>
#include <math.h>

#define NC     1000
#define NUNIT  4000     // class x col-half x y-half
#define NCOMB  2000
#define DIM    2048
#define HALF   1024
#define NBATCH 8192
#define YHALF  4096     // rows per y-half
#define MAXN   512      // sidx capacity; n_p ~ Poisson(4.1), max ~20

typedef float f32x4 __attribute__((ext_vector_type(4)));
typedef int   i32x4 __attribute__((ext_vector_type(4)));

// ws layout (bytes):
// [0, 16777216)           S: partial sums, [4000][1024] floats (4 KB/unit)
// [16777216, 16793216)    nP: int[4000]
// [16793216, 16809216)    lossP: float[4000]

// Grid 4000 = 1000 classes x 2 col-halves x 2 y-halves; 256 threads, f32x4.
// Unit u: c=u>>2, h=(u>>1)&1, p=u&1. Scans only y[p*4096 .. p*4096+4096)
// (16 KB, total scan volume unchanged vs R11) and gathers ~4.1 rows.
// 4000 units > 2048 resident slots -> second round is placed on draining CUs
// at FULL occupancy = the balance mechanism R8/R9/R10 couldn't deliver.
__global__ __launch_bounds__(256) void k_main(
        const int*   __restrict__ y,
        const float* __restrict__ feat,
        float* __restrict__ S,        // [4000][1024]
        int*   __restrict__ nP,       // [4000]
        float* __restrict__ lossP,    // [4000]
        const float* __restrict__ centers) {
    const int u = blockIdx.x;
    const int c = u >> 2;
    const int h = (u >> 1) & 1;
    const int p = u & 1;
    const int t = threadIdx.x;
    const int col = h * HALF + 4 * t;

    const f32x4 cen = *(const f32x4*)(centers + (size_t)c * DIM + col);

    __shared__ unsigned short sidx[MAXN];
    __shared__ int scur;
    if (t == 0) scur = 0;
    __syncthreads();

    // scan this unit's y-half: 1024 int4 -> 4 per thread
    const i32x4* y4 = (const i32x4*)y;
    const int jbase = p * (YHALF / 4);
    #pragma unroll
    for (int k = 0; k < 4; ++k) {
        int j = jbase + t + k * 256;
        i32x4 v = y4[j];
        int base = 4 * j;
        if (v.x == c) sidx[atomicAdd(&scur, 1) & (MAXN - 1)] = (unsigned short)(base + 0);
        if (v.y == c) sidx[atomicAdd(&scur, 1) & (MAXN - 1)] = (unsigned short)(base + 1);
        if (v.z == c) sidx[atomicAdd(&scur, 1) & (MAXN - 1)] = (unsigned short)(base + 2);
        if (v.w == c) sidx[atomicAdd(&scur, 1) & (MAXN - 1)] = (unsigned short)(base + 3);
    }
    __syncthreads();
    const int n = scur;

    f32x4 acc = (f32x4)(0.f);
    f32x4 sq  = (f32x4)(0.f);

    int r = 0;
    for (; r + 4 <= n; r += 4) {
        int i0 = sidx[r], i1 = sidx[r+1], i2 = sidx[r+2], i3 = sidx[r+3];
        f32x4 v0 = *(const f32x4*)(feat + (size_t)i0 * DIM + col);
        f32x4 v1 = *(const f32x4*)(feat + (size_t)i1 * DIM + col);
        f32x4 v2 = *(const f32x4*)(feat + (size_t)i2 * DIM + col);
        f32x4 v3 = *(const f32x4*)(feat + (size_t)i3 * DIM + col);
        acc += v0 + v1 + v2 + v3;
        f32x4 d0 = v0 - cen, d1 = v1 - cen, d2 = v2 - cen, d3 = v3 - cen;
        sq += d0*d0 + d1*d1 + d2*d2 + d3*d3;
    }
    for (; r < n; ++r) {
        f32x4 v0 = *(const f32x4*)(feat + (size_t)sidx[r] * DIM + col);
        acc += v0;
        f32x4 d0 = v0 - cen;
        sq += d0 * d0;
    }
    float lsum = sq.x + sq.y + sq.z + sq.w;

    // write partial sum (16B-aligned coalesced)
    *(f32x4*)(S + (size_t)u * HALF + 4 * t) = acc;

    // block-reduce lsum -> per-unit loss partial
    for (int sh = 32; sh > 0; sh >>= 1) lsum += __shfl_down(lsum, sh);
    __shared__ float red[4];
    if ((t & 63) == 0) red[t >> 6] = lsum;
    __syncthreads();
    if (t == 0) {
        lossP[u] = red[0] + red[1] + red[2] + red[3];
        nP[u] = n;
    }
}

// Grid 2000 = 1000 classes x 2 col-halves; merges the two y-half partials.
__global__ __launch_bounds__(256) void k_comb(
        const float* __restrict__ S,
        const int*   __restrict__ nP,
        const float* __restrict__ centers,
        float* __restrict__ grad_out) {   // d_out + 1
    const int c = blockIdx.x >> 1;
    const int h = blockIdx.x & 1;
    const int t = threadIdx.x;
    const int col = h * HALF + 4 * t;
    const int u0 = c * 4 + h * 2;

    const int n = nP[u0] + nP[u0 + 1];
    f32x4 s0 = *(const f32x4*)(S + (size_t)u0 * HALF + 4 * t);
    f32x4 s1 = *(const f32x4*)(S + (size_t)(u0 + 1) * HALF + 4 * t);
    const f32x4 cen = *(const f32x4*)(centers + (size_t)c * DIM + col);

    f32x4 g = (f32x4)(0.f);
    if (n > 0) {
        float fn = (float)n;
        float coeff = fn / (1.0f + fn);
        g = coeff * (cen - (s0 + s1) * (1.0f / fn));
    }
    float* go = grad_out + (size_t)c * DIM + col;   // odd base -> scalar stores
    go[0] = g.x; go[1] = g.y; go[2] = g.z; go[3] = g.w;
}

__global__ void k_loss(const float* __restrict__ lossP, float* __restrict__ out) {
    __shared__ float s[256];
    int t = threadIdx.x;
    float v = 0.f;
    for (int i = t; i < NUNIT; i += 256) v += lossP[i];
    s[t] = v;
    __syncthreads();
    for (int off = 128; off > 0; off >>= 1) {
        if (t < off) s[t] += s[t + off];
        __syncthreads();
    }
    if (t == 0) out[0] = 0.5f * sqrtf(s[0]) / (float)NBATCH;
}

extern "C" void kernel_launch(void* const* d_in, const int* in_sizes, int n_in,
                              void* d_out, int out_size, void* d_ws, size_t ws_size,
                              hipStream_t stream) {
    const int*   y       = (const int*)d_in[0];
    const float* feat    = (const float*)d_in[1];
    const float* centers = (const float*)d_in[2];
    float* out = (float*)d_out;

    char* ws = (char*)d_ws;
    float* S     = (float*)ws;
    int*   nP    = (int*)(ws + 16777216);
    float* lossP = (float*)(ws + 16793216);

    k_main<<<NUNIT, 256, 0, stream>>>(y, feat, S, nP, lossP, centers);
    k_comb<<<NCOMB, 256, 0, stream>>>(S, nP, centers, out + 1);
    k_loss<<<1, 256, 0, stream>>>(lossP, out);
}